// Round 3
// baseline (495.281 us; speedup 1.0000x reference)
//
#include <hip/hip_runtime.h>

// ---------- types ----------
typedef short short8 __attribute__((ext_vector_type(8)));
typedef unsigned short ushort8 __attribute__((ext_vector_type(8)));
typedef float float4v __attribute__((ext_vector_type(4)));

// ---------- bf16 helpers (bit-level) ----------
__device__ __forceinline__ unsigned short f2bf(float f) {
    union { float f; unsigned u; } v; v.f = f;
    unsigned r = v.u + 0x7fffu + ((v.u >> 16) & 1u);   // RNE
    return (unsigned short)(r >> 16);
}

// ---------- async global->LDS, 16B per lane ----------
__device__ __forceinline__ void async_copy16(const void* g, void* l) {
    __builtin_amdgcn_global_load_lds(
        (__attribute__((address_space(1))) void*)g,
        (__attribute__((address_space(3))) void*)l,
        16, 0, 0);
}

// ---------- fp32 -> bf16 cast (vectorized) ----------
__global__ __launch_bounds__(256) void cast_bf16_kernel(
        const float* __restrict__ in, unsigned short* __restrict__ out, int n) {
    int i4 = (blockIdx.x * 256 + threadIdx.x) * 4;
    if (i4 < n) {
        float4 f = *(const float4*)(in + i4);
        ushort4 u;
        u.x = f2bf(f.x); u.y = f2bf(f.y); u.z = f2bf(f.z); u.w = f2bf(f.w);
        *(ushort4*)(out + i4) = u;
    }
}

// encoder cast with per-batch row padding 77 -> 96  ([4,77,2048] -> [4,96,2048])
__global__ __launch_bounds__(256) void cast_enc_pad_kernel(
        const float* __restrict__ in, unsigned short* __restrict__ out) {
    int i4 = blockIdx.x * 256 + threadIdx.x;         // float4 index
    if (i4 < 4 * 77 * 2048 / 4) {
        const int per_b = 77 * 2048 / 4;             // 39424
        int b = i4 / per_b;
        int rem = i4 - b * per_b;
        float4 f = *(const float4*)(in + (size_t)i4 * 4);
        ushort4 u;
        u.x = f2bf(f.x); u.y = f2bf(f.y); u.z = f2bf(f.z); u.w = f2bf(f.w);
        *(ushort4*)(out + ((size_t)b * (96 * 2048 / 4) + rem) * 4) = u;
    }
}

// batched small casts (grid.y selects tensor)
struct CastBatch {
    const float* src[8];
    unsigned short* dst[8];
    int n[8];
};
__global__ __launch_bounds__(256) void cast_batch_kernel(CastBatch cb) {
    const int t = blockIdx.y;
    const int n = cb.n[t];
    int i4 = (blockIdx.x * 256 + threadIdx.x) * 4;
    if (i4 < n) {
        float4 f = *(const float4*)(cb.src[t] + i4);
        ushort4 u;
        u.x = f2bf(f.x); u.y = f2bf(f.y); u.z = f2bf(f.z); u.w = f2bf(f.w);
        *(ushort4*)(cb.dst[t] + i4) = u;
    }
}

// ---------- bf16 GEMM core 128x128 (kept for the small K/V projections) ----------
template<int EPI>
__device__ __forceinline__ void gemm_core(
        const unsigned short* __restrict__ A,
        const unsigned short* __restrict__ B,
        float* __restrict__ Cf,
        unsigned short* __restrict__ Cb,
        const float* __restrict__ bias,
        const float* __restrict__ resid,
        int Mclamp, int N, int K, int bm, int bn) {
    __shared__ unsigned short As[128 * 64];   // 16 KB
    __shared__ unsigned short Bs[128 * 64];   // 16 KB

    const int tid  = threadIdx.x;
    const int lane = tid & 63;
    const int wave = tid >> 6;
    const int wm   = (wave >> 1) * 64;
    const int wn   = (wave & 1) * 64;
    const int lr   = lane & 15;
    const int lq   = lane >> 4;

    float4v acc[4][4] = {};

    const unsigned short* aptr[4];
    const unsigned short* bptr[4];
    #pragma unroll
    for (int r = 0; r < 4; ++r) {
        const int linear = r * 256 + tid;
        const int row = linear >> 3;
        const int c = (linear & 7) ^ (row & 7);
        int ar = bm + row; if (ar >= Mclamp) ar = Mclamp - 1;
        aptr[r] = A + (size_t)ar * K + c * 8;
        bptr[r] = B + (size_t)(bn + row) * K + c * 8;
    }

    for (int ks = 0; ks < K; ks += 64) {
        #pragma unroll
        for (int r = 0; r < 4; ++r) {
            async_copy16(aptr[r] + ks, (char*)As + (size_t)(r * 256 + tid) * 16);
            async_copy16(bptr[r] + ks, (char*)Bs + (size_t)(r * 256 + tid) * 16);
        }
        __syncthreads();

        #pragma unroll
        for (int kw = 0; kw < 2; ++kw) {
            short8 af[4], bfr[4];
            #pragma unroll
            for (int i = 0; i < 4; ++i) {
                const int row = wm + i * 16 + lr;
                af[i] = *(const short8*)(As + row * 64 + (((kw << 2) | lq) ^ (row & 7)) * 8);
            }
            #pragma unroll
            for (int j = 0; j < 4; ++j) {
                const int row = wn + j * 16 + lr;
                bfr[j] = *(const short8*)(Bs + row * 64 + (((kw << 2) | lq) ^ (row & 7)) * 8);
            }
            #pragma unroll
            for (int i = 0; i < 4; ++i)
                #pragma unroll
                for (int j = 0; j < 4; ++j)
                    acc[i][j] = __builtin_amdgcn_mfma_f32_16x16x32_bf16(
                                    af[i], bfr[j], acc[i][j], 0, 0, 0);
        }
        __syncthreads();
    }

    #pragma unroll
    for (int i = 0; i < 4; ++i) {
        #pragma unroll
        for (int r = 0; r < 4; ++r) {
            const int row = bm + wm + i * 16 + lq * 4 + r;
            const size_t base = (size_t)row * N;
            #pragma unroll
            for (int j = 0; j < 4; ++j) {
                const int col = bn + wn + j * 16 + lr;
                const float v = acc[i][j][r];
                const size_t idx = base + col;
                if (EPI == 2)      Cf[idx] = v + bias[col] + resid[idx];
                else if (EPI == 1) Cb[idx] = f2bf(v);
                else               Cf[idx] = v;
            }
        }
    }
}

// all four K/V/iK/iV projections in one launch -> bf16 outputs
__global__ __launch_bounds__(256) void gemm_kv4_kernel(
        const unsigned short* __restrict__ Aenc,   // [384,2048] per-batch padded
        const unsigned short* __restrict__ Aid,    // [128,2048]
        const unsigned short* __restrict__ Wk,
        const unsigned short* __restrict__ Wv,
        const unsigned short* __restrict__ Wik,
        const unsigned short* __restrict__ Wiv,
        unsigned short* __restrict__ Kb, unsigned short* __restrict__ Vb,
        unsigned short* __restrict__ IKb, unsigned short* __restrict__ IVb,
        int N, int K) {
    const int z = blockIdx.z;
    const int bm = blockIdx.x * 128;
    const int Mrows = (z < 2) ? 384 : 128;
    if (bm >= Mrows) return;
    const unsigned short* A = (z < 2) ? Aenc : Aid;
    const unsigned short* B = (z == 0) ? Wk : (z == 1) ? Wv : (z == 2) ? Wik : Wiv;
    unsigned short* C = (z == 0) ? Kb : (z == 1) ? Vb : (z == 2) ? IKb : IVb;
    gemm_core<1>(A, B, nullptr, C, nullptr, nullptr, Mrows, N, K,
                 bm, blockIdx.y * 128);
}

// ---------- 256x256 8-wave K-ring pipelined GEMM (big projections) ----------
// C[m,n] = sum_k A[m,k]*B[n,k]. Requires K % 128 == 0 (NSLOT >= 4 even),
// M,N multiples of 256, grid.x % 8 == 0.
//
// Pipeline: 4-slot ring, slot = 32-wide K-slice (A 256x32 + B 256x32, each a
// DEDICATED contiguous 16 KB array so global_load_lds' lane-linear dest
// constraint holds). While computing slot j: slot j+1 is landed+validated,
// slots j+2/j+3 in flight (8 loads), slot j+3 being staged (2 loads/phase).
// Boundary at end of slot j: s_waitcnt vmcnt(8) -> s_barrier validates slot
// j+1 for ALL waves BEFORE any ds_read of it (this ordering was the round-2
// race: reads preceded the validating barrier). Tail: vmcnt 8 -> 4 -> 0.
// LDS layout: 64B rows, phys chunk = lq ^ ((row>>1)&3) -> exact 2-way bank
// aliasing (free, m136); source pre-permuted with same involution, dest linear.
template<int EPI>
__global__ __launch_bounds__(512) void gemm256_kernel(
        const unsigned short* __restrict__ A,
        const unsigned short* __restrict__ B,
        float* __restrict__ Cf,
        unsigned short* __restrict__ Cb,
        const float* __restrict__ bias,
        const float* __restrict__ resid,
        int N, int K, int tn) {           // tn = tiles along N
    __shared__ unsigned short Ar[4][256 * 32];   // 4 x 16 KB
    __shared__ unsigned short Br[4][256 * 32];   // 4 x 16 KB  (128 KB total)

    const int tid  = threadIdx.x;
    const int lane = tid & 63;
    const int wave = tid >> 6;
    const int wm   = (wave >> 2) * 128;   // 2 wave-rows
    const int wn   = (wave & 3) * 64;     // 4 wave-cols
    const int l15  = lane & 15;
    const int lq   = lane >> 4;

    // XCD-bijective block swizzle (gridDim.x % 8 == 0)
    int wg = blockIdx.x;
    const int q = gridDim.x >> 3;
    wg = (wg & 7) * q + (wg >> 3);
    const int mt = wg / tn;
    const int nt = wg - mt * tn;
    const int bm = mt * 256;
    const int bn = nt * 256;

    float4v acc[8][4] = {};

    // staging per-thread constants: 2 chunk-loads/slot for A, 2 for B.
    // linear d = g*512+tid -> row = d>>2, phys chunk = d&3,
    // logical chunk = phys ^ ((row>>1)&3)  (involution).
    const unsigned short* aS[2];
    const unsigned short* bS[2];
    int dOff[2];
    #pragma unroll
    for (int g = 0; g < 2; ++g) {
        const int d = g * 512 + tid;
        const int row = d >> 2;
        const int cl = (d & 3) ^ ((row >> 1) & 3);
        aS[g] = A + (size_t)(bm + row) * K + cl * 8;
        bS[g] = B + (size_t)(bn + row) * K + cl * 8;
        dOff[g] = d * 16;
    }

    auto stageA = [&](int sj) {
        const int s = sj & 3;
        #pragma unroll
        for (int g = 0; g < 2; ++g)
            async_copy16(aS[g] + sj * 32, (char*)&Ar[s][0] + dOff[g]);
    };
    auto stageB = [&](int sj) {
        const int s = sj & 3;
        #pragma unroll
        for (int g = 0; g < 2; ++g)
            async_copy16(bS[g] + sj * 32, (char*)&Br[s][0] + dOff[g]);
    };

    const int NSLOT = K >> 5;     // 32-wide K slots (K=1280 -> 40)
    // prologue: slots 0..2 issued; validate slot 0 (oldest 4 loads) only.
    stageA(0); stageB(0); stageA(1); stageB(1); stageA(2); stageB(2);
    asm volatile("s_waitcnt vmcnt(8)" ::: "memory");
    __builtin_amdgcn_s_barrier();
    __builtin_amdgcn_sched_barrier(0);

    for (int j = 0; j < NSLOT; ++j) {
        const int s = j & 3;
        const unsigned short* As_ = &Ar[s][0];
        const unsigned short* Bs_ = &Br[s][0];
        short8 af0[4], af1[4], bf[4];

        // ---- phase 0: A rows wm..wm+63 x B (16 MFMA) ----
        #pragma unroll
        for (int ii = 0; ii < 4; ++ii) {
            const int row = wm + ii * 16 + l15;
            af0[ii] = *(const short8*)(As_ + row * 32 + ((lq ^ ((row >> 1) & 3)) << 3));
        }
        #pragma unroll
        for (int j2 = 0; j2 < 4; ++j2) {
            const int row = wn + j2 * 16 + l15;
            bf[j2] = *(const short8*)(Bs_ + row * 32 + ((lq ^ ((row >> 1) & 3)) << 3));
        }
        if (j + 3 < NSLOT) stageA(j + 3);   // ring (j+3)&3 = (j-1)&3: reads done
        __builtin_amdgcn_s_barrier();
        asm volatile("s_waitcnt lgkmcnt(0)" ::: "memory");
        __builtin_amdgcn_sched_barrier(0);
        __builtin_amdgcn_s_setprio(1);
        #pragma unroll
        for (int ii = 0; ii < 4; ++ii)
            #pragma unroll
            for (int j2 = 0; j2 < 4; ++j2)
                acc[ii][j2] = __builtin_amdgcn_mfma_f32_16x16x32_bf16(
                                  af0[ii], bf[j2], acc[ii][j2], 0, 0, 0);
        __builtin_amdgcn_s_setprio(0);
        __builtin_amdgcn_s_barrier();
        __builtin_amdgcn_sched_barrier(0);

        // ---- phase 1: A rows wm+64..wm+127 x same B frags (16 MFMA) ----
        #pragma unroll
        for (int ii = 0; ii < 4; ++ii) {
            const int row = wm + 64 + ii * 16 + l15;
            af1[ii] = *(const short8*)(As_ + row * 32 + ((lq ^ ((row >> 1) & 3)) << 3));
        }
        if (j + 3 < NSLOT) stageB(j + 3);
        __builtin_amdgcn_s_barrier();
        asm volatile("s_waitcnt lgkmcnt(0)" ::: "memory");
        __builtin_amdgcn_sched_barrier(0);
        __builtin_amdgcn_s_setprio(1);
        #pragma unroll
        for (int ii = 0; ii < 4; ++ii)
            #pragma unroll
            for (int j2 = 0; j2 < 4; ++j2)
                acc[4 + ii][j2] = __builtin_amdgcn_mfma_f32_16x16x32_bf16(
                                      af1[ii], bf[j2], acc[4 + ii][j2], 0, 0, 0);
        __builtin_amdgcn_s_setprio(0);

        // ---- boundary: validate slot j+1 for all waves (vmcnt -> barrier
        //      -> only then next slot's ds_reads). Counted, never drained. ----
        if (j <= NSLOT - 4)      { asm volatile("s_waitcnt vmcnt(8)" ::: "memory"); }
        else if (j == NSLOT - 3) { asm volatile("s_waitcnt vmcnt(4)" ::: "memory"); }
        else if (j <  NSLOT - 1) { asm volatile("s_waitcnt vmcnt(0)" ::: "memory"); }
        __builtin_amdgcn_s_barrier();
        __builtin_amdgcn_sched_barrier(0);
    }

    // C/D layout: col=lane&15, row=(lane>>4)*4+reg   [m89-verified]
    #pragma unroll
    for (int i = 0; i < 8; ++i) {
        #pragma unroll
        for (int r = 0; r < 4; ++r) {
            const int row = bm + wm + i * 16 + lq * 4 + r;
            const size_t base = (size_t)row * N;
            #pragma unroll
            for (int j = 0; j < 4; ++j) {
                const int col = bn + wn + j * 16 + l15;
                const float v = acc[i][j][r];
                const size_t idx = base + col;
                if (EPI == 2)      Cf[idx] = v + bias[col] + resid[idx];
                else if (EPI == 1) Cb[idx] = f2bf(v);
                else               Cf[idx] = v;
            }
        }
    }
}

// ---------- MFMA fused dual attention ----------
#define VT_STRIDE 136
__global__ __launch_bounds__(256) void attn_mfma_kernel(
        const unsigned short* __restrict__ Q,     // [16384,1280] bf16
        const unsigned short* __restrict__ Kb,    // [384,1280]  bf16, rows b*96+t
        const unsigned short* __restrict__ Vb,    // [384,1280]  bf16
        const unsigned short* __restrict__ IKb,   // [128,1280]  bf16, rows b*32+t
        const unsigned short* __restrict__ IVb,   // [128,1280]  bf16
        unsigned short* __restrict__ Cmb) {       // [16384,1280] bf16
    const int b = blockIdx.z;
    const int h = blockIdx.y;
    const int hoff = h * 64;
    const int qbase = blockIdx.x * 64;
    const int tid = threadIdx.x;
    const int lane = tid & 63;
    const int wave = tid >> 6;
    const int l15 = lane & 15;
    const int quad = lane >> 4;

    __shared__ unsigned short Vt[64 * VT_STRIDE];  // [d][key] cross 0..95, id 96..127
    __shared__ unsigned short Pl[64 * VT_STRIDE];  // [qrow][key]

    for (int i = tid; i < 96 * 8; i += 256) {
        const int c = i / 96;
        const int key = i - c * 96;
        short8 v = *(const short8*)(Vb + (size_t)(b * 96 + key) * 1280 + hoff + c * 8);
        #pragma unroll
        for (int j = 0; j < 8; ++j)
            Vt[(c * 8 + j) * VT_STRIDE + key] = (unsigned short)v[j];
    }
    {
        const int c = tid >> 5;
        const int key = tid & 31;
        short8 v = *(const short8*)(IVb + (size_t)(b * 32 + key) * 1280 + hoff + c * 8);
        #pragma unroll
        for (int j = 0; j < 8; ++j)
            Vt[(c * 8 + j) * VT_STRIDE + 96 + key] = (unsigned short)v[j];
    }
    __syncthreads();

    const int qrow = b * 4096 + qbase + wave * 16 + l15;
    const unsigned short* qp = Q + (size_t)qrow * 1280 + hoff + quad * 8;
    const short8 aQ0 = *(const short8*)(qp);
    const short8 aQ1 = *(const short8*)(qp + 32);

    const float scale = 0.125f;
    float lC[4] = {0.f, 0.f, 0.f, 0.f};
    float lI[4] = {0.f, 0.f, 0.f, 0.f};

    #pragma unroll
    for (int t = 0; t < 5; ++t) {
        const unsigned short* kp = Kb + (size_t)(b * 96 + t * 16 + l15) * 1280 + hoff + quad * 8;
        const short8 bK0 = *(const short8*)(kp);
        const short8 bK1 = *(const short8*)(kp + 32);
        float4v s = {};
        s = __builtin_amdgcn_mfma_f32_16x16x32_bf16(aQ0, bK0, s, 0, 0, 0);
        s = __builtin_amdgcn_mfma_f32_16x16x32_bf16(aQ1, bK1, s, 0, 0, 0);
        #pragma unroll
        for (int r = 0; r < 4; ++r) {
            float p = __expf(s[r] * scale);
            if (t == 4 && l15 >= 13) p = 0.f;   // keys 77..79 masked
            lC[r] += p;
            Pl[(wave * 16 + quad * 4 + r) * VT_STRIDE + t * 16 + l15] = f2bf(p);
        }
    }
    #pragma unroll
    for (int r = 0; r < 4; ++r)
        Pl[(wave * 16 + quad * 4 + r) * VT_STRIDE + 80 + l15] = 0;

    #pragma unroll
    for (int t = 0; t < 2; ++t) {
        const unsigned short* kp = IKb + (size_t)(b * 32 + t * 16 + l15) * 1280 + hoff + quad * 8;
        const short8 bK0 = *(const short8*)(kp);
        const short8 bK1 = *(const short8*)(kp + 32);
        float4v s = {};
        s = __builtin_amdgcn_mfma_f32_16x16x32_bf16(aQ0, bK0, s, 0, 0, 0);
        s = __builtin_amdgcn_mfma_f32_16x16x32_bf16(aQ1, bK1, s, 0, 0, 0);
        #pragma unroll
        for (int r = 0; r < 4; ++r) {
            const float p = __expf(s[r] * scale);
            lI[r] += p;
            Pl[(wave * 16 + quad * 4 + r) * VT_STRIDE + 96 + t * 16 + l15] = f2bf(p);
        }
    }

    #pragma unroll
    for (int m = 1; m <= 8; m <<= 1) {
        #pragma unroll
        for (int r = 0; r < 4; ++r) {
            lC[r] += __shfl_xor(lC[r], m);
            lI[r] += __shfl_xor(lI[r], m);
        }
    }
    __syncthreads();

    float4v oC[4] = {};
    float4v oI[4] = {};
    #pragma unroll
    for (int kt = 0; kt < 3; ++kt) {
        const short8 aP = *(const short8*)(Pl + (wave * 16 + l15) * VT_STRIDE + kt * 32 + quad * 8);
        #pragma unroll
        for (int td = 0; td < 4; ++td) {
            const short8 bV = *(const short8*)(Vt + (td * 16 + l15) * VT_STRIDE + kt * 32 + quad * 8);
            oC[td] = __builtin_amdgcn_mfma_f32_16x16x32_bf16(aP, bV, oC[td], 0, 0, 0);
        }
    }
    {
        const short8 aP = *(const short8*)(Pl + (wave * 16 + l15) * VT_STRIDE + 96 + quad * 8);
        #pragma unroll
        for (int td = 0; td < 4; ++td) {
            const short8 bV = *(const short8*)(Vt + (td * 16 + l15) * VT_STRIDE + 96 + quad * 8);
            oI[td] = __builtin_amdgcn_mfma_f32_16x16x32_bf16(aP, bV, oI[td], 0, 0, 0);
        }
    }

    float rc[4], ri[4];
    #pragma unroll
    for (int r = 0; r < 4; ++r) { rc[r] = 1.f / lC[r]; ri[r] = 1.f / lI[r]; }

    #pragma unroll
    for (int td = 0; td < 4; ++td) {
        #pragma unroll
        for (int r = 0; r < 4; ++r) {
            const int row = b * 4096 + qbase + wave * 16 + quad * 4 + r;
            const int col = hoff + td * 16 + l15;
            Cmb[(size_t)row * 1280 + col] = f2bf(oC[td][r] * rc[r] + oI[td][r] * ri[r]);
        }
    }
}

// ---------- host launch ----------
extern "C" void kernel_launch(void* const* d_in, const int* in_sizes, int n_in,
                              void* d_out, int out_size, void* d_ws, size_t ws_size,
                              hipStream_t stream) {
    const float* hs  = (const float*)d_in[0];   // [4,4096,1280]
    const float* enc = (const float*)d_in[1];   // [4,77,2048]
    const float* idm = (const float*)d_in[2];   // [4,32,2048]
    const float* Wq  = (const float*)d_in[3];
    const float* Wk  = (const float*)d_in[4];
    const float* Wv  = (const float*)d_in[5];
    const float* Wik = (const float*)d_in[6];
    const float* Wiv = (const float*)d_in[7];
    const float* Wo  = (const float*)d_in[8];
    const float* bo  = (const float*)d_in[9];
    float* out = (float*)d_out;

    char* ws = (char*)d_ws;
    size_t off = 0;
    auto carve = [&](size_t bytes) {
        char* p = ws + off;
        off += (bytes + 255) & ~(size_t)255;
        return p;
    };

    unsigned short* Xh   = (unsigned short*)carve(16384ULL * 1280 * 2); // hs bf16, later 'combined'
    unsigned short* Wq_b = (unsigned short*)carve(1280ULL * 1280 * 2);
    unsigned short* Wk_b = (unsigned short*)carve(1280ULL * 2048 * 2);
    unsigned short* Wv_b = (unsigned short*)carve(1280ULL * 2048 * 2);
    unsigned short* Wik_b= (unsigned short*)carve(1280ULL * 2048 * 2);
    unsigned short* Wiv_b= (unsigned short*)carve(1280ULL * 2048 * 2);
    unsigned short* Wo_b = (unsigned short*)carve(1280ULL * 1280 * 2);
    unsigned short* Encb = (unsigned short*)carve(384ULL * 2048 * 2);  // per-batch padded 96 rows
    unsigned short* Idb  = (unsigned short*)carve(128ULL * 2048 * 2);
    unsigned short* Qb   = (unsigned short*)carve(16384ULL * 1280 * 2);
    unsigned short* Kb   = (unsigned short*)carve(384ULL * 1280 * 2);
    unsigned short* Vb   = (unsigned short*)carve(384ULL * 1280 * 2);
    unsigned short* IKb  = (unsigned short*)carve(128ULL * 1280 * 2);
    unsigned short* IVb  = (unsigned short*)carve(128ULL * 1280 * 2);
    (void)ws_size; (void)in_sizes; (void)n_in; (void)out_size;

    cast_bf16_kernel<<<(4 * 4096 * 1280 / 4 + 255) / 256, 256, 0, stream>>>(
        hs, Xh, 4 * 4096 * 1280);
    cast_enc_pad_kernel<<<(4 * 77 * 2048 / 4 + 255) / 256, 256, 0, stream>>>(enc, Encb);

    CastBatch cb;
    cb.src[0] = Wq;  cb.dst[0] = Wq_b;  cb.n[0] = 1280 * 1280;
    cb.src[1] = Wk;  cb.dst[1] = Wk_b;  cb.n[1] = 1280 * 2048;
    cb.src[2] = Wv;  cb.dst[2] = Wv_b;  cb.n[2] = 1280 * 2048;
    cb.src[3] = Wik; cb.dst[3] = Wik_b; cb.n[3] = 1280 * 2048;
    cb.src[4] = Wiv; cb.dst[4] = Wiv_b; cb.n[4] = 1280 * 2048;
    cb.src[5] = Wo;  cb.dst[5] = Wo_b;  cb.n[5] = 1280 * 1280;
    cb.src[6] = idm; cb.dst[6] = Idb;   cb.n[6] = 4 * 32 * 2048;
    cb.src[7] = nullptr; cb.dst[7] = nullptr; cb.n[7] = 0;
    cast_batch_kernel<<<dim3((1280 * 2048 / 4 + 255) / 256, 7), 256, 0, stream>>>(cb);

    // Q = hs @ Wq^T -> bf16   (256^2 K-ring: 64x5 = 320 tiles, %8==0)
    gemm256_kernel<1><<<dim3(64 * 5), 512, 0, stream>>>(
        Xh, Wq_b, nullptr, Qb, nullptr, nullptr, 1280, 1280, 5);

    // K/V/iK/iV projections -> bf16 (z=0..3)
    gemm_kv4_kernel<<<dim3(3, 10, 4), 256, 0, stream>>>(
        Encb, Idb, Wk_b, Wv_b, Wik_b, Wiv_b, Kb, Vb, IKb, IVb, 1280, 2048);

    // fused MFMA attention -> combined (reuses Xh)
    attn_mfma_kernel<<<dim3(64, 20, 4), 256, 0, stream>>>(Qb, Kb, Vb, IKb, IVb, Xh);

    // out = combined @ Wo^T + bo + residual
    gemm256_kernel<2><<<dim3(64 * 5), 512, 0, stream>>>(
        Xh, Wo_b, out, nullptr, bo, hs, 1280, 1280, 5);
}

// Round 4
// 461.848 us; speedup vs baseline: 1.0724x; 1.0724x over previous
//
#include <hip/hip_runtime.h>

// ---------- types ----------
typedef short short8 __attribute__((ext_vector_type(8)));
typedef unsigned short ushort8 __attribute__((ext_vector_type(8)));
typedef float float4v __attribute__((ext_vector_type(4)));

// ---------- bf16 helpers (bit-level) ----------
__device__ __forceinline__ unsigned short f2bf(float f) {
    union { float f; unsigned u; } v; v.f = f;
    unsigned r = v.u + 0x7fffu + ((v.u >> 16) & 1u);   // RNE
    return (unsigned short)(r >> 16);
}

// ---------- async global->LDS, 16B per lane ----------
__device__ __forceinline__ void async_copy16(const void* g, void* l) {
    __builtin_amdgcn_global_load_lds(
        (__attribute__((address_space(1))) void*)g,
        (__attribute__((address_space(3))) void*)l,
        16, 0, 0);
}

// ---------- fp32 -> bf16 cast (vectorized) ----------
__global__ __launch_bounds__(256) void cast_bf16_kernel(
        const float* __restrict__ in, unsigned short* __restrict__ out, int n) {
    int i4 = (blockIdx.x * 256 + threadIdx.x) * 4;
    if (i4 < n) {
        float4 f = *(const float4*)(in + i4);
        ushort4 u;
        u.x = f2bf(f.x); u.y = f2bf(f.y); u.z = f2bf(f.z); u.w = f2bf(f.w);
        *(ushort4*)(out + i4) = u;
    }
}

// encoder cast with per-batch row padding 77 -> 96  ([4,77,2048] -> [4,96,2048])
__global__ __launch_bounds__(256) void cast_enc_pad_kernel(
        const float* __restrict__ in, unsigned short* __restrict__ out) {
    int i4 = blockIdx.x * 256 + threadIdx.x;         // float4 index
    if (i4 < 4 * 77 * 2048 / 4) {
        const int per_b = 77 * 2048 / 4;             // 39424
        int b = i4 / per_b;
        int rem = i4 - b * per_b;
        float4 f = *(const float4*)(in + (size_t)i4 * 4);
        ushort4 u;
        u.x = f2bf(f.x); u.y = f2bf(f.y); u.z = f2bf(f.z); u.w = f2bf(f.w);
        *(ushort4*)(out + ((size_t)b * (96 * 2048 / 4) + rem) * 4) = u;
    }
}

// batched small casts (grid.y selects tensor)
struct CastBatch {
    const float* src[8];
    unsigned short* dst[8];
    int n[8];
};
__global__ __launch_bounds__(256) void cast_batch_kernel(CastBatch cb) {
    const int t = blockIdx.y;
    const int n = cb.n[t];
    int i4 = (blockIdx.x * 256 + threadIdx.x) * 4;
    if (i4 < n) {
        float4 f = *(const float4*)(cb.src[t] + i4);
        ushort4 u;
        u.x = f2bf(f.x); u.y = f2bf(f.y); u.z = f2bf(f.z); u.w = f2bf(f.w);
        *(ushort4*)(cb.dst[t] + i4) = u;
    }
}

// ---------- 64x128-tile bf16 GEMM for the K/V projections ----------
// M-dim is tiny (384 enc rows / 128 id rows): 128^2 tiles gave only 80 active
// blocks (31% of CUs, 1/CU, no overlap) -> staging-latency-bound ~32 iters of
// 32 KB. 64x128 tiles double CU coverage (160 blocks) and cut staged bytes to
// 24 KB/iter. Same proven single-buffer stage->sync->compute->sync structure
// and XOR chunk swizzle as the 128^2 core.
__global__ __launch_bounds__(256) void gemm_kv4_kernel(
        const unsigned short* __restrict__ Aenc,   // [384,2048] per-batch padded
        const unsigned short* __restrict__ Aid,    // [128,2048]
        const unsigned short* __restrict__ Wk,
        const unsigned short* __restrict__ Wv,
        const unsigned short* __restrict__ Wik,
        const unsigned short* __restrict__ Wiv,
        unsigned short* __restrict__ Kb, unsigned short* __restrict__ Vb,
        unsigned short* __restrict__ IKb, unsigned short* __restrict__ IVb,
        int N, int K) {
    const int z = blockIdx.z;
    const int bm = blockIdx.x * 64;
    const int Mrows = (z < 2) ? 384 : 128;
    if (bm >= Mrows) return;
    const unsigned short* A = (z < 2) ? Aenc : Aid;
    const unsigned short* B = (z == 0) ? Wk : (z == 1) ? Wv : (z == 2) ? Wik : Wiv;
    unsigned short* C = (z == 0) ? Kb : (z == 1) ? Vb : (z == 2) ? IKb : IVb;
    const int bn = blockIdx.y * 128;

    __shared__ unsigned short As[64 * 64];    // 8 KB
    __shared__ unsigned short Bs[128 * 64];   // 16 KB

    const int tid  = threadIdx.x;
    const int lane = tid & 63;
    const int wave = tid >> 6;
    const int wm   = (wave >> 1) * 32;
    const int wn   = (wave & 1) * 64;
    const int lr   = lane & 15;
    const int lq   = lane >> 4;

    float4v acc[2][4] = {};

    // A: 64 rows x 8 chunks = 512 chunk-slots -> 2 per thread
    // B: 128 rows x 8 chunks = 1024 -> 4 per thread
    const unsigned short* aptr[2];
    const unsigned short* bptr[4];
    #pragma unroll
    for (int r = 0; r < 2; ++r) {
        const int linear = r * 256 + tid;
        const int row = linear >> 3;
        const int c = (linear & 7) ^ (row & 7);
        aptr[r] = A + (size_t)(bm + row) * K + c * 8;
    }
    #pragma unroll
    for (int r = 0; r < 4; ++r) {
        const int linear = r * 256 + tid;
        const int row = linear >> 3;
        const int c = (linear & 7) ^ (row & 7);
        bptr[r] = B + (size_t)(bn + row) * K + c * 8;
    }

    for (int ks = 0; ks < K; ks += 64) {
        #pragma unroll
        for (int r = 0; r < 2; ++r)
            async_copy16(aptr[r] + ks, (char*)As + (size_t)(r * 256 + tid) * 16);
        #pragma unroll
        for (int r = 0; r < 4; ++r)
            async_copy16(bptr[r] + ks, (char*)Bs + (size_t)(r * 256 + tid) * 16);
        __syncthreads();

        #pragma unroll
        for (int kw = 0; kw < 2; ++kw) {
            short8 af[2], bfr[4];
            #pragma unroll
            for (int i = 0; i < 2; ++i) {
                const int row = wm + i * 16 + lr;
                af[i] = *(const short8*)(As + row * 64 + (((kw << 2) | lq) ^ (row & 7)) * 8);
            }
            #pragma unroll
            for (int j = 0; j < 4; ++j) {
                const int row = wn + j * 16 + lr;
                bfr[j] = *(const short8*)(Bs + row * 64 + (((kw << 2) | lq) ^ (row & 7)) * 8);
            }
            #pragma unroll
            for (int i = 0; i < 2; ++i)
                #pragma unroll
                for (int j = 0; j < 4; ++j)
                    acc[i][j] = __builtin_amdgcn_mfma_f32_16x16x32_bf16(
                                    af[i], bfr[j], acc[i][j], 0, 0, 0);
        }
        __syncthreads();
    }

    // C/D layout: col=lane&15, row=(lane>>4)*4+reg   [m89-verified]
    #pragma unroll
    for (int i = 0; i < 2; ++i) {
        #pragma unroll
        for (int r = 0; r < 4; ++r) {
            const int row = bm + wm + i * 16 + lq * 4 + r;
            const size_t base = (size_t)row * N;
            #pragma unroll
            for (int j = 0; j < 4; ++j) {
                const int col = bn + wn + j * 16 + lr;
                C[base + col] = f2bf(acc[i][j][r]);
            }
        }
    }
}

// ---------- 256x256 8-wave pipelined GEMM (big projections) ----------
// Round-1 structure (best measured at this shape: 108 us, ~490 TF, matches
// the m102 reference curve for K=N=1280). Two barriers per K-tile:
//   vmcnt(8) [tile t landed, t+1 in flight] -> barrier -> ds_read kw0 ->
//   32 MFMA -> ds_read kw1 -> lgkmcnt(0) -> barrier -> stage(t+2, counted
//   not drained) -> setprio(1) 32 MFMA setprio(0).
// Finer phasing (r3 K-ring, 4 barriers/32-K) REGRESSED to 126 us at this
// shape — do not re-add without within-probe A/B.
template<int EPI>
__global__ __launch_bounds__(512) void gemm256_kernel(
        const unsigned short* __restrict__ A,
        const unsigned short* __restrict__ B,
        float* __restrict__ Cf,
        unsigned short* __restrict__ Cb,
        const float* __restrict__ bias,
        const float* __restrict__ resid,
        int N, int K, int tn) {           // tn = tiles along N
    __shared__ unsigned short As[2][256 * 64];   // 64 KB
    __shared__ unsigned short Bs[2][256 * 64];   // 64 KB

    const int tid  = threadIdx.x;
    const int lane = tid & 63;
    const int wave = tid >> 6;
    const int wm   = (wave >> 2) * 128;   // 2 wave-rows
    const int wn   = (wave & 3) * 64;     // 4 wave-cols
    const int l15  = lane & 15;
    const int lq   = lane >> 4;

    // XCD-bijective block swizzle (gridDim.x % 8 == 0)
    int wg = blockIdx.x;
    const int q = gridDim.x >> 3;
    wg = (wg & 7) * q + (wg >> 3);
    const int mt = wg / tn;
    const int nt = wg - mt * tn;
    const int bm = mt * 256;
    const int bn = nt * 256;

    float4v acc[8][4] = {};

    // staging addresses: linear chunk = r*512+tid; row = linear>>3,
    // physical chunk = linear&7, logical chunk = phys ^ (row&7).
    const unsigned short* aptr[4];
    const unsigned short* bptr[4];
    #pragma unroll
    for (int r = 0; r < 4; ++r) {
        const int linear = r * 512 + tid;
        const int row = linear >> 3;
        const int c = (linear & 7) ^ (row & 7);
        aptr[r] = A + (size_t)(bm + row) * K + c * 8;
        bptr[r] = B + (size_t)(bn + row) * K + c * 8;
    }

    auto stage = [&](int ks, int b) {
        #pragma unroll
        for (int r = 0; r < 4; ++r)
            async_copy16(aptr[r] + ks, (char*)&As[b][0] + (r * 512 + tid) * 16);
        #pragma unroll
        for (int r = 0; r < 4; ++r)
            async_copy16(bptr[r] + ks, (char*)&Bs[b][0] + (r * 512 + tid) * 16);
    };

    const int NT = K >> 6;
    stage(0, 0);
    stage(64, 1);

    for (int t = 0; t < NT; ++t) {
        const int cur = t & 1;
        if (t == NT - 1) {
            asm volatile("s_waitcnt vmcnt(0)" ::: "memory");
        } else {
            asm volatile("s_waitcnt vmcnt(8)" ::: "memory");   // tile t landed, t+1 stays in flight
        }
        __builtin_amdgcn_s_barrier();
        __builtin_amdgcn_sched_barrier(0);

        short8 a0[8], b0[4], a1[8], b1[4];
        #pragma unroll
        for (int i = 0; i < 8; ++i) {
            const int row = wm + i * 16 + l15;
            a0[i] = *(const short8*)(&As[cur][row * 64 + ((lq ^ (row & 7)) << 3)]);
        }
        #pragma unroll
        for (int j = 0; j < 4; ++j) {
            const int row = wn + j * 16 + l15;
            b0[j] = *(const short8*)(&Bs[cur][row * 64 + ((lq ^ (row & 7)) << 3)]);
        }
        #pragma unroll
        for (int i = 0; i < 8; ++i)
            #pragma unroll
            for (int j = 0; j < 4; ++j)
                acc[i][j] = __builtin_amdgcn_mfma_f32_16x16x32_bf16(
                                a0[i], b0[j], acc[i][j], 0, 0, 0);
        #pragma unroll
        for (int i = 0; i < 8; ++i) {
            const int row = wm + i * 16 + l15;
            a1[i] = *(const short8*)(&As[cur][row * 64 + (((4 | lq) ^ (row & 7)) << 3)]);
        }
        #pragma unroll
        for (int j = 0; j < 4; ++j) {
            const int row = wn + j * 16 + l15;
            b1[j] = *(const short8*)(&Bs[cur][row * 64 + (((4 | lq) ^ (row & 7)) << 3)]);
        }
        // all reads of buf[cur] retired before anyone overwrites it
        asm volatile("s_waitcnt lgkmcnt(0)" ::: "memory");
        __builtin_amdgcn_sched_barrier(0);
        if (t < NT - 2) {
            __builtin_amdgcn_s_barrier();
            stage((t + 2) << 6, cur);   // overlaps with kw1 MFMA cluster below
        }
        __builtin_amdgcn_s_setprio(1);
        #pragma unroll
        for (int i = 0; i < 8; ++i)
            #pragma unroll
            for (int j = 0; j < 4; ++j)
                acc[i][j] = __builtin_amdgcn_mfma_f32_16x16x32_bf16(
                                a1[i], b1[j], acc[i][j], 0, 0, 0);
        __builtin_amdgcn_s_setprio(0);
    }

    // C/D layout: col=lane&15, row=(lane>>4)*4+reg   [m89-verified]
    #pragma unroll
    for (int i = 0; i < 8; ++i) {
        #pragma unroll
        for (int r = 0; r < 4; ++r) {
            const int row = bm + wm + i * 16 + lq * 4 + r;
            const size_t base = (size_t)row * N;
            #pragma unroll
            for (int j = 0; j < 4; ++j) {
                const int col = bn + wn + j * 16 + l15;
                const float v = acc[i][j][r];
                const size_t idx = base + col;
                if (EPI == 2)      Cf[idx] = v + bias[col] + resid[idx];
                else if (EPI == 1) Cb[idx] = f2bf(v);
                else               Cf[idx] = v;
            }
        }
    }
}

// ---------- MFMA fused dual attention ----------
#define VT_STRIDE 136
__global__ __launch_bounds__(256) void attn_mfma_kernel(
        const unsigned short* __restrict__ Q,     // [16384,1280] bf16
        const unsigned short* __restrict__ Kb,    // [384,1280]  bf16, rows b*96+t
        const unsigned short* __restrict__ Vb,    // [384,1280]  bf16
        const unsigned short* __restrict__ IKb,   // [128,1280]  bf16, rows b*32+t
        const unsigned short* __restrict__ IVb,   // [128,1280]  bf16
        unsigned short* __restrict__ Cmb) {       // [16384,1280] bf16
    const int b = blockIdx.z;
    const int h = blockIdx.y;
    const int hoff = h * 64;
    const int qbase = blockIdx.x * 64;
    const int tid = threadIdx.x;
    const int lane = tid & 63;
    const int wave = tid >> 6;
    const int l15 = lane & 15;
    const int quad = lane >> 4;

    __shared__ unsigned short Vt[64 * VT_STRIDE];  // [d][key] cross 0..95, id 96..127
    __shared__ unsigned short Pl[64 * VT_STRIDE];  // [qrow][key]

    for (int i = tid; i < 96 * 8; i += 256) {
        const int c = i / 96;
        const int key = i - c * 96;
        short8 v = *(const short8*)(Vb + (size_t)(b * 96 + key) * 1280 + hoff + c * 8);
        #pragma unroll
        for (int j = 0; j < 8; ++j)
            Vt[(c * 8 + j) * VT_STRIDE + key] = (unsigned short)v[j];
    }
    {
        const int c = tid >> 5;
        const int key = tid & 31;
        short8 v = *(const short8*)(IVb + (size_t)(b * 32 + key) * 1280 + hoff + c * 8);
        #pragma unroll
        for (int j = 0; j < 8; ++j)
            Vt[(c * 8 + j) * VT_STRIDE + 96 + key] = (unsigned short)v[j];
    }
    __syncthreads();

    const int qrow = b * 4096 + qbase + wave * 16 + l15;
    const unsigned short* qp = Q + (size_t)qrow * 1280 + hoff + quad * 8;
    const short8 aQ0 = *(const short8*)(qp);
    const short8 aQ1 = *(const short8*)(qp + 32);

    const float scale = 0.125f;
    float lC[4] = {0.f, 0.f, 0.f, 0.f};
    float lI[4] = {0.f, 0.f, 0.f, 0.f};

    #pragma unroll
    for (int t = 0; t < 5; ++t) {
        const unsigned short* kp = Kb + (size_t)(b * 96 + t * 16 + l15) * 1280 + hoff + quad * 8;
        const short8 bK0 = *(const short8*)(kp);
        const short8 bK1 = *(const short8*)(kp + 32);
        float4v s = {};
        s = __builtin_amdgcn_mfma_f32_16x16x32_bf16(aQ0, bK0, s, 0, 0, 0);
        s = __builtin_amdgcn_mfma_f32_16x16x32_bf16(aQ1, bK1, s, 0, 0, 0);
        #pragma unroll
        for (int r = 0; r < 4; ++r) {
            float p = __expf(s[r] * scale);
            if (t == 4 && l15 >= 13) p = 0.f;   // keys 77..79 masked
            lC[r] += p;
            Pl[(wave * 16 + quad * 4 + r) * VT_STRIDE + t * 16 + l15] = f2bf(p);
        }
    }
    #pragma unroll
    for (int r = 0; r < 4; ++r)
        Pl[(wave * 16 + quad * 4 + r) * VT_STRIDE + 80 + l15] = 0;

    #pragma unroll
    for (int t = 0; t < 2; ++t) {
        const unsigned short* kp = IKb + (size_t)(b * 32 + t * 16 + l15) * 1280 + hoff + quad * 8;
        const short8 bK0 = *(const short8*)(kp);
        const short8 bK1 = *(const short8*)(kp + 32);
        float4v s = {};
        s = __builtin_amdgcn_mfma_f32_16x16x32_bf16(aQ0, bK0, s, 0, 0, 0);
        s = __builtin_amdgcn_mfma_f32_16x16x32_bf16(aQ1, bK1, s, 0, 0, 0);
        #pragma unroll
        for (int r = 0; r < 4; ++r) {
            const float p = __expf(s[r] * scale);
            lI[r] += p;
            Pl[(wave * 16 + quad * 4 + r) * VT_STRIDE + 96 + t * 16 + l15] = f2bf(p);
        }
    }

    #pragma unroll
    for (int m = 1; m <= 8; m <<= 1) {
        #pragma unroll
        for (int r = 0; r < 4; ++r) {
            lC[r] += __shfl_xor(lC[r], m);
            lI[r] += __shfl_xor(lI[r], m);
        }
    }
    __syncthreads();

    float4v oC[4] = {};
    float4v oI[4] = {};
    #pragma unroll
    for (int kt = 0; kt < 3; ++kt) {
        const short8 aP = *(const short8*)(Pl + (wave * 16 + l15) * VT_STRIDE + kt * 32 + quad * 8);
        #pragma unroll
        for (int td = 0; td < 4; ++td) {
            const short8 bV = *(const short8*)(Vt + (td * 16 + l15) * VT_STRIDE + kt * 32 + quad * 8);
            oC[td] = __builtin_amdgcn_mfma_f32_16x16x32_bf16(aP, bV, oC[td], 0, 0, 0);
        }
    }
    {
        const short8 aP = *(const short8*)(Pl + (wave * 16 + l15) * VT_STRIDE + 96 + quad * 8);
        #pragma unroll
        for (int td = 0; td < 4; ++td) {
            const short8 bV = *(const short8*)(Vt + (td * 16 + l15) * VT_STRIDE + 96 + quad * 8);
            oI[td] = __builtin_amdgcn_mfma_f32_16x16x32_bf16(aP, bV, oI[td], 0, 0, 0);
        }
    }

    float rc[4], ri[4];
    #pragma unroll
    for (int r = 0; r < 4; ++r) { rc[r] = 1.f / lC[r]; ri[r] = 1.f / lI[r]; }

    #pragma unroll
    for (int td = 0; td < 4; ++td) {
        #pragma unroll
        for (int r = 0; r < 4; ++r) {
            const int row = b * 4096 + qbase + wave * 16 + quad * 4 + r;
            const int col = hoff + td * 16 + l15;
            Cmb[(size_t)row * 1280 + col] = f2bf(oC[td][r] * rc[r] + oI[td][r] * ri[r]);
        }
    }
}

// ---------- host launch ----------
extern "C" void kernel_launch(void* const* d_in, const int* in_sizes, int n_in,
                              void* d_out, int out_size, void* d_ws, size_t ws_size,
                              hipStream_t stream) {
    const float* hs  = (const float*)d_in[0];   // [4,4096,1280]
    const float* enc = (const float*)d_in[1];   // [4,77,2048]
    const float* idm = (const float*)d_in[2];   // [4,32,2048]
    const float* Wq  = (const float*)d_in[3];
    const float* Wk  = (const float*)d_in[4];
    const float* Wv  = (const float*)d_in[5];
    const float* Wik = (const float*)d_in[6];
    const float* Wiv = (const float*)d_in[7];
    const float* Wo  = (const float*)d_in[8];
    const float* bo  = (const float*)d_in[9];
    float* out = (float*)d_out;

    char* ws = (char*)d_ws;
    size_t off = 0;
    auto carve = [&](size_t bytes) {
        char* p = ws + off;
        off += (bytes + 255) & ~(size_t)255;
        return p;
    };

    unsigned short* Xh   = (unsigned short*)carve(16384ULL * 1280 * 2); // hs bf16, later 'combined'
    unsigned short* Wq_b = (unsigned short*)carve(1280ULL * 1280 * 2);
    unsigned short* Wk_b = (unsigned short*)carve(1280ULL * 2048 * 2);
    unsigned short* Wv_b = (unsigned short*)carve(1280ULL * 2048 * 2);
    unsigned short* Wik_b= (unsigned short*)carve(1280ULL * 2048 * 2);
    unsigned short* Wiv_b= (unsigned short*)carve(1280ULL * 2048 * 2);
    unsigned short* Wo_b = (unsigned short*)carve(1280ULL * 1280 * 2);
    unsigned short* Encb = (unsigned short*)carve(384ULL * 2048 * 2);  // per-batch padded 96 rows
    unsigned short* Idb  = (unsigned short*)carve(128ULL * 2048 * 2);
    unsigned short* Qb   = (unsigned short*)carve(16384ULL * 1280 * 2);
    unsigned short* Kb   = (unsigned short*)carve(384ULL * 1280 * 2);
    unsigned short* Vb   = (unsigned short*)carve(384ULL * 1280 * 2);
    unsigned short* IKb  = (unsigned short*)carve(128ULL * 1280 * 2);
    unsigned short* IVb  = (unsigned short*)carve(128ULL * 1280 * 2);
    (void)ws_size; (void)in_sizes; (void)n_in; (void)out_size;

    cast_bf16_kernel<<<(4 * 4096 * 1280 / 4 + 255) / 256, 256, 0, stream>>>(
        hs, Xh, 4 * 4096 * 1280);
    cast_enc_pad_kernel<<<(4 * 77 * 2048 / 4 + 255) / 256, 256, 0, stream>>>(enc, Encb);

    CastBatch cb;
    cb.src[0] = Wq;  cb.dst[0] = Wq_b;  cb.n[0] = 1280 * 1280;
    cb.src[1] = Wk;  cb.dst[1] = Wk_b;  cb.n[1] = 1280 * 2048;
    cb.src[2] = Wv;  cb.dst[2] = Wv_b;  cb.n[2] = 1280 * 2048;
    cb.src[3] = Wik; cb.dst[3] = Wik_b; cb.n[3] = 1280 * 2048;
    cb.src[4] = Wiv; cb.dst[4] = Wiv_b; cb.n[4] = 1280 * 2048;
    cb.src[5] = Wo;  cb.dst[5] = Wo_b;  cb.n[5] = 1280 * 1280;
    cb.src[6] = idm; cb.dst[6] = Idb;   cb.n[6] = 4 * 32 * 2048;
    cb.src[7] = nullptr; cb.dst[7] = nullptr; cb.n[7] = 0;
    cast_batch_kernel<<<dim3((1280 * 2048 / 4 + 255) / 256, 7), 256, 0, stream>>>(cb);

    // Q = hs @ Wq^T -> bf16   (256^2 round-1 pipeline: 64x5 = 320 tiles, %8==0)
    gemm256_kernel<1><<<dim3(64 * 5), 512, 0, stream>>>(
        Xh, Wq_b, nullptr, Qb, nullptr, nullptr, 1280, 1280, 5);

    // K/V/iK/iV projections -> bf16 (z=0..3), 64x128 tiles: 160 active blocks
    gemm_kv4_kernel<<<dim3(6, 10, 4), 256, 0, stream>>>(
        Encb, Idb, Wk_b, Wv_b, Wik_b, Wiv_b, Kb, Vb, IKb, IVb, 1280, 2048);

    // fused MFMA attention -> combined (reuses Xh)
    attn_mfma_kernel<<<dim3(64, 20, 4), 256, 0, stream>>>(Qb, Kb, Vb, IKb, IVb, Xh);

    // out = combined @ Wo^T + bo + residual
    gemm256_kernel<2><<<dim3(64 * 5), 512, 0, stream>>>(
        Xh, Wo_b, out, nullptr, bo, hs, 1280, 1280, 5);
}

// Round 5
// 423.689 us; speedup vs baseline: 1.1690x; 1.0901x over previous
//
#include <hip/hip_runtime.h>

// ---------- types ----------
typedef short short8 __attribute__((ext_vector_type(8)));
typedef unsigned short ushort8 __attribute__((ext_vector_type(8)));
typedef float float4v __attribute__((ext_vector_type(4)));

// ---------- bf16 helpers (bit-level) ----------
__device__ __forceinline__ unsigned short f2bf(float f) {
    union { float f; unsigned u; } v; v.f = f;
    unsigned r = v.u + 0x7fffu + ((v.u >> 16) & 1u);   // RNE
    return (unsigned short)(r >> 16);
}

// ---------- async global->LDS, 16B per lane ----------
__device__ __forceinline__ void async_copy16(const void* g, void* l) {
    __builtin_amdgcn_global_load_lds(
        (__attribute__((address_space(1))) void*)g,
        (__attribute__((address_space(3))) void*)l,
        16, 0, 0);
}

// ---------- fp32 -> bf16 cast (vectorized) ----------
__global__ __launch_bounds__(256) void cast_bf16_kernel(
        const float* __restrict__ in, unsigned short* __restrict__ out, int n) {
    int i4 = (blockIdx.x * 256 + threadIdx.x) * 4;
    if (i4 < n) {
        float4 f = *(const float4*)(in + i4);
        ushort4 u;
        u.x = f2bf(f.x); u.y = f2bf(f.y); u.z = f2bf(f.z); u.w = f2bf(f.w);
        *(ushort4*)(out + i4) = u;
    }
}

// encoder cast with per-batch row padding 77 -> 96  ([4,77,2048] -> [4,96,2048])
__global__ __launch_bounds__(256) void cast_enc_pad_kernel(
        const float* __restrict__ in, unsigned short* __restrict__ out) {
    int i4 = blockIdx.x * 256 + threadIdx.x;         // float4 index
    if (i4 < 4 * 77 * 2048 / 4) {
        const int per_b = 77 * 2048 / 4;             // 39424
        int b = i4 / per_b;
        int rem = i4 - b * per_b;
        float4 f = *(const float4*)(in + (size_t)i4 * 4);
        ushort4 u;
        u.x = f2bf(f.x); u.y = f2bf(f.y); u.z = f2bf(f.z); u.w = f2bf(f.w);
        *(ushort4*)(out + ((size_t)b * (96 * 2048 / 4) + rem) * 4) = u;
    }
}

// batched small casts (grid.y selects tensor)
struct CastBatch {
    const float* src[8];
    unsigned short* dst[8];
    int n[8];
};
__global__ __launch_bounds__(256) void cast_batch_kernel(CastBatch cb) {
    const int t = blockIdx.y;
    const int n = cb.n[t];
    int i4 = (blockIdx.x * 256 + threadIdx.x) * 4;
    if (i4 < n) {
        float4 f = *(const float4*)(cb.src[t] + i4);
        ushort4 u;
        u.x = f2bf(f.x); u.y = f2bf(f.y); u.z = f2bf(f.z); u.w = f2bf(f.w);
        *(ushort4*)(cb.dst[t] + i4) = u;
    }
}

// ---------- 64x128-tile bf16 GEMM for the K/V projections ----------
// (unchanged from round 4 — measured net win)
__global__ __launch_bounds__(256) void gemm_kv4_kernel(
        const unsigned short* __restrict__ Aenc,   // [384,2048] per-batch padded
        const unsigned short* __restrict__ Aid,    // [128,2048]
        const unsigned short* __restrict__ Wk,
        const unsigned short* __restrict__ Wv,
        const unsigned short* __restrict__ Wik,
        const unsigned short* __restrict__ Wiv,
        unsigned short* __restrict__ Kb, unsigned short* __restrict__ Vb,
        unsigned short* __restrict__ IKb, unsigned short* __restrict__ IVb,
        int N, int K) {
    const int z = blockIdx.z;
    const int bm = blockIdx.x * 64;
    const int Mrows = (z < 2) ? 384 : 128;
    if (bm >= Mrows) return;
    const unsigned short* A = (z < 2) ? Aenc : Aid;
    const unsigned short* B = (z == 0) ? Wk : (z == 1) ? Wv : (z == 2) ? Wik : Wiv;
    unsigned short* C = (z == 0) ? Kb : (z == 1) ? Vb : (z == 2) ? IKb : IVb;
    const int bn = blockIdx.y * 128;

    __shared__ unsigned short As[64 * 64];    // 8 KB
    __shared__ unsigned short Bs[128 * 64];   // 16 KB

    const int tid  = threadIdx.x;
    const int lane = tid & 63;
    const int wave = tid >> 6;
    const int wm   = (wave >> 1) * 32;
    const int wn   = (wave & 1) * 64;
    const int lr   = lane & 15;
    const int lq   = lane >> 4;

    float4v acc[2][4] = {};

    const unsigned short* aptr[2];
    const unsigned short* bptr[4];
    #pragma unroll
    for (int r = 0; r < 2; ++r) {
        const int linear = r * 256 + tid;
        const int row = linear >> 3;
        const int c = (linear & 7) ^ (row & 7);
        aptr[r] = A + (size_t)(bm + row) * K + c * 8;
    }
    #pragma unroll
    for (int r = 0; r < 4; ++r) {
        const int linear = r * 256 + tid;
        const int row = linear >> 3;
        const int c = (linear & 7) ^ (row & 7);
        bptr[r] = B + (size_t)(bn + row) * K + c * 8;
    }

    for (int ks = 0; ks < K; ks += 64) {
        #pragma unroll
        for (int r = 0; r < 2; ++r)
            async_copy16(aptr[r] + ks, (char*)As + (size_t)(r * 256 + tid) * 16);
        #pragma unroll
        for (int r = 0; r < 4; ++r)
            async_copy16(bptr[r] + ks, (char*)Bs + (size_t)(r * 256 + tid) * 16);
        __syncthreads();

        #pragma unroll
        for (int kw = 0; kw < 2; ++kw) {
            short8 af[2], bfr[4];
            #pragma unroll
            for (int i = 0; i < 2; ++i) {
                const int row = wm + i * 16 + lr;
                af[i] = *(const short8*)(As + row * 64 + (((kw << 2) | lq) ^ (row & 7)) * 8);
            }
            #pragma unroll
            for (int j = 0; j < 4; ++j) {
                const int row = wn + j * 16 + lr;
                bfr[j] = *(const short8*)(Bs + row * 64 + (((kw << 2) | lq) ^ (row & 7)) * 8);
            }
            #pragma unroll
            for (int i = 0; i < 2; ++i)
                #pragma unroll
                for (int j = 0; j < 4; ++j)
                    acc[i][j] = __builtin_amdgcn_mfma_f32_16x16x32_bf16(
                                    af[i], bfr[j], acc[i][j], 0, 0, 0);
        }
        __syncthreads();
    }

    #pragma unroll
    for (int i = 0; i < 2; ++i) {
        #pragma unroll
        for (int r = 0; r < 4; ++r) {
            const int row = bm + wm + i * 16 + lq * 4 + r;
            const size_t base = (size_t)row * N;
            #pragma unroll
            for (int j = 0; j < 4; ++j) {
                const int col = bn + wn + j * 16 + lr;
                C[base + col] = f2bf(acc[i][j][r]);
            }
        }
    }
}

// ---------- 256x320-tile BK=32 GEMM (big projections) ----------
// Geometry fix for M=16384,N=1280,K=1280: grid = 64 x 4 = 256 blocks = EXACT
// one block/CU, no second scheduling round (round-1/4's 320-block grid wasted
// 37.5% in the 64-block tail). Staged bytes/FLOP also improves: 36 KB per
// 5.24 MFLOP (6.9 KB/MFLOP vs 7.6 at 256^2). Same proven 2-barrier loop:
//   vmcnt(counted, per-wave) -> barrier -> 14 ds_read_b128 -> lgkmcnt(0) ->
//   barrier -> stage(t+2) -> setprio(1) 40 MFMA setprio(0).
// B tile is 320 rows = 2.5 loads/thread: waves 0-3 carry a 5th load, so the
// counted vmcnt is per-wave (5 vs 4) — each wave validates ITS OWN loads
// before the barrier, then the whole tile is valid for everyone (r3 lesson).
// LDS 72 KB: As 2x16KB + Bs 2x20KB. Rows are 64B, chunk XOR (row>>1)&3 ->
// exact 2-way bank aliasing (free, m136); source pre-permuted, dest linear.
template<int EPI>
__global__ __launch_bounds__(512, 2) void gemm320_kernel(
        const unsigned short* __restrict__ A,
        const unsigned short* __restrict__ B,
        float* __restrict__ Cf,
        unsigned short* __restrict__ Cb,
        const float* __restrict__ bias,
        const float* __restrict__ resid,
        int N, int K, int tn) {           // tn = tiles along N (=4)
    __shared__ unsigned short As[2][256 * 32];   // 2 x 16 KB
    __shared__ unsigned short Bs[2][320 * 32];   // 2 x 20 KB

    const int tid  = threadIdx.x;
    const int lane = tid & 63;
    const int wave = tid >> 6;
    const int wm   = (wave >> 1) * 64;    // 4 wave-rows
    const int wn   = (wave & 1) * 160;    // 2 wave-cols
    const int l15  = lane & 15;
    const int lq   = lane >> 4;

    // XCD-bijective block swizzle (gridDim.x % 8 == 0)
    int wg = blockIdx.x;
    const int q = gridDim.x >> 3;
    wg = (wg & 7) * q + (wg >> 3);
    const int mt = wg / tn;
    const int nt = wg - mt * tn;
    const int bm = mt * 256;
    const int bn = nt * 320;

    float4v acc[4][10] = {};

    // staging address precompute. slot d -> row = d>>2, phys chunk = d&3,
    // logical chunk = phys ^ ((row>>1)&3) (involution; exact 2-way banks).
    const unsigned short* aS[2];
    const unsigned short* bS[2];
    const unsigned short* bS2;
    int dA[2], dB[2], dB2;
    #pragma unroll
    for (int g = 0; g < 2; ++g) {
        const int d = g * 512 + tid;
        const int row = d >> 2;
        const int c = (d & 3) ^ ((row >> 1) & 3);
        aS[g] = A + (size_t)(bm + row) * K + c * 8;
        bS[g] = B + (size_t)(bn + row) * K + c * 8;
        dA[g] = d * 16;
        dB[g] = d * 16;
    }
    {   // B rows 256..319: one extra load for threads 0..255 (waves 0-3)
        const int t2 = tid & 255;
        const int d = 1024 + t2;
        const int row = d >> 2;              // 256..319
        const int c = (d & 3) ^ ((row >> 1) & 3);
        bS2 = B + (size_t)(bn + row) * K + c * 8;
        dB2 = d * 16;
    }

    auto stage = [&](int t) {
        const int b = t & 1;
        #pragma unroll
        for (int g = 0; g < 2; ++g)
            async_copy16(aS[g] + t * 32, (char*)&As[b][0] + dA[g]);
        #pragma unroll
        for (int g = 0; g < 2; ++g)
            async_copy16(bS[g] + t * 32, (char*)&Bs[b][0] + dB[g]);
        if (wave < 4)
            async_copy16(bS2 + t * 32, (char*)&Bs[b][0] + dB2);
    };

    const int NT = K >> 5;        // 40
    stage(0);
    stage(1);

    for (int t = 0; t < NT; ++t) {
        const int cur = t & 1;
        // validate tile t: wait until only tile t+1's own loads remain.
        if (t == NT - 1) {
            asm volatile("s_waitcnt vmcnt(0)" ::: "memory");
        } else if (wave < 4) {
            asm volatile("s_waitcnt vmcnt(5)" ::: "memory");
        } else {
            asm volatile("s_waitcnt vmcnt(4)" ::: "memory");
        }
        __builtin_amdgcn_s_barrier();
        __builtin_amdgcn_sched_barrier(0);

        short8 af[4], bf[10];
        #pragma unroll
        for (int i = 0; i < 4; ++i) {
            const int row = wm + i * 16 + l15;
            af[i] = *(const short8*)(&As[cur][row * 32 + ((lq ^ ((row >> 1) & 3)) << 3)]);
        }
        #pragma unroll
        for (int j = 0; j < 10; ++j) {
            const int row = wn + j * 16 + l15;
            bf[j] = *(const short8*)(&Bs[cur][row * 32 + ((lq ^ ((row >> 1) & 3)) << 3)]);
        }
        asm volatile("s_waitcnt lgkmcnt(0)" ::: "memory");
        __builtin_amdgcn_sched_barrier(0);
        if (t < NT - 2) {
            __builtin_amdgcn_s_barrier();   // all waves done reading buf[cur]
            stage(t + 2);                   // overwrite buf[cur]; overlaps MFMA
        }
        __builtin_amdgcn_s_setprio(1);
        #pragma unroll
        for (int i = 0; i < 4; ++i)
            #pragma unroll
            for (int j = 0; j < 10; ++j)
                acc[i][j] = __builtin_amdgcn_mfma_f32_16x16x32_bf16(
                                af[i], bf[j], acc[i][j], 0, 0, 0);
        __builtin_amdgcn_s_setprio(0);
    }

    // C/D layout: col=lane&15, row=(lane>>4)*4+reg   [m89-verified]
    #pragma unroll
    for (int i = 0; i < 4; ++i) {
        #pragma unroll
        for (int r = 0; r < 4; ++r) {
            const int row = bm + wm + i * 16 + lq * 4 + r;
            const size_t base = (size_t)row * N;
            #pragma unroll
            for (int j = 0; j < 10; ++j) {
                const int col = bn + wn + j * 16 + l15;
                const float v = acc[i][j][r];
                const size_t idx = base + col;
                if (EPI == 2)      Cf[idx] = v + bias[col] + resid[idx];
                else if (EPI == 1) Cb[idx] = f2bf(v);
                else               Cf[idx] = v;
            }
        }
    }
}

// ---------- MFMA fused dual attention ----------
#define VT_STRIDE 136
__global__ __launch_bounds__(256) void attn_mfma_kernel(
        const unsigned short* __restrict__ Q,     // [16384,1280] bf16
        const unsigned short* __restrict__ Kb,    // [384,1280]  bf16, rows b*96+t
        const unsigned short* __restrict__ Vb,    // [384,1280]  bf16
        const unsigned short* __restrict__ IKb,   // [128,1280]  bf16, rows b*32+t
        const unsigned short* __restrict__ IVb,   // [128,1280]  bf16
        unsigned short* __restrict__ Cmb) {       // [16384,1280] bf16
    const int b = blockIdx.z;
    const int h = blockIdx.y;
    const int hoff = h * 64;
    const int qbase = blockIdx.x * 64;
    const int tid = threadIdx.x;
    const int lane = tid & 63;
    const int wave = tid >> 6;
    const int l15 = lane & 15;
    const int quad = lane >> 4;

    __shared__ unsigned short Vt[64 * VT_STRIDE];  // [d][key] cross 0..95, id 96..127
    __shared__ unsigned short Pl[64 * VT_STRIDE];  // [qrow][key]

    for (int i = tid; i < 96 * 8; i += 256) {
        const int c = i / 96;
        const int key = i - c * 96;
        short8 v = *(const short8*)(Vb + (size_t)(b * 96 + key) * 1280 + hoff + c * 8);
        #pragma unroll
        for (int j = 0; j < 8; ++j)
            Vt[(c * 8 + j) * VT_STRIDE + key] = (unsigned short)v[j];
    }
    {
        const int c = tid >> 5;
        const int key = tid & 31;
        short8 v = *(const short8*)(IVb + (size_t)(b * 32 + key) * 1280 + hoff + c * 8);
        #pragma unroll
        for (int j = 0; j < 8; ++j)
            Vt[(c * 8 + j) * VT_STRIDE + 96 + key] = (unsigned short)v[j];
    }
    __syncthreads();

    const int qrow = b * 4096 + qbase + wave * 16 + l15;
    const unsigned short* qp = Q + (size_t)qrow * 1280 + hoff + quad * 8;
    const short8 aQ0 = *(const short8*)(qp);
    const short8 aQ1 = *(const short8*)(qp + 32);

    const float scale = 0.125f;
    float lC[4] = {0.f, 0.f, 0.f, 0.f};
    float lI[4] = {0.f, 0.f, 0.f, 0.f};

    #pragma unroll
    for (int t = 0; t < 5; ++t) {
        const unsigned short* kp = Kb + (size_t)(b * 96 + t * 16 + l15) * 1280 + hoff + quad * 8;
        const short8 bK0 = *(const short8*)(kp);
        const short8 bK1 = *(const short8*)(kp + 32);
        float4v s = {};
        s = __builtin_amdgcn_mfma_f32_16x16x32_bf16(aQ0, bK0, s, 0, 0, 0);
        s = __builtin_amdgcn_mfma_f32_16x16x32_bf16(aQ1, bK1, s, 0, 0, 0);
        #pragma unroll
        for (int r = 0; r < 4; ++r) {
            float p = __expf(s[r] * scale);
            if (t == 4 && l15 >= 13) p = 0.f;   // keys 77..79 masked
            lC[r] += p;
            Pl[(wave * 16 + quad * 4 + r) * VT_STRIDE + t * 16 + l15] = f2bf(p);
        }
    }
    #pragma unroll
    for (int r = 0; r < 4; ++r)
        Pl[(wave * 16 + quad * 4 + r) * VT_STRIDE + 80 + l15] = 0;

    #pragma unroll
    for (int t = 0; t < 2; ++t) {
        const unsigned short* kp = IKb + (size_t)(b * 32 + t * 16 + l15) * 1280 + hoff + quad * 8;
        const short8 bK0 = *(const short8*)(kp);
        const short8 bK1 = *(const short8*)(kp + 32);
        float4v s = {};
        s = __builtin_amdgcn_mfma_f32_16x16x32_bf16(aQ0, bK0, s, 0, 0, 0);
        s = __builtin_amdgcn_mfma_f32_16x16x32_bf16(aQ1, bK1, s, 0, 0, 0);
        #pragma unroll
        for (int r = 0; r < 4; ++r) {
            const float p = __expf(s[r] * scale);
            lI[r] += p;
            Pl[(wave * 16 + quad * 4 + r) * VT_STRIDE + 96 + t * 16 + l15] = f2bf(p);
        }
    }

    #pragma unroll
    for (int m = 1; m <= 8; m <<= 1) {
        #pragma unroll
        for (int r = 0; r < 4; ++r) {
            lC[r] += __shfl_xor(lC[r], m);
            lI[r] += __shfl_xor(lI[r], m);
        }
    }
    __syncthreads();

    float4v oC[4] = {};
    float4v oI[4] = {};
    #pragma unroll
    for (int kt = 0; kt < 3; ++kt) {
        const short8 aP = *(const short8*)(Pl + (wave * 16 + l15) * VT_STRIDE + kt * 32 + quad * 8);
        #pragma unroll
        for (int td = 0; td < 4; ++td) {
            const short8 bV = *(const short8*)(Vt + (td * 16 + l15) * VT_STRIDE + kt * 32 + quad * 8);
            oC[td] = __builtin_amdgcn_mfma_f32_16x16x32_bf16(aP, bV, oC[td], 0, 0, 0);
        }
    }
    {
        const short8 aP = *(const short8*)(Pl + (wave * 16 + l15) * VT_STRIDE + 96 + quad * 8);
        #pragma unroll
        for (int td = 0; td < 4; ++td) {
            const short8 bV = *(const short8*)(Vt + (td * 16 + l15) * VT_STRIDE + 96 + quad * 8);
            oI[td] = __builtin_amdgcn_mfma_f32_16x16x32_bf16(aP, bV, oI[td], 0, 0, 0);
        }
    }

    float rc[4], ri[4];
    #pragma unroll
    for (int r = 0; r < 4; ++r) { rc[r] = 1.f / lC[r]; ri[r] = 1.f / lI[r]; }

    #pragma unroll
    for (int td = 0; td < 4; ++td) {
        #pragma unroll
        for (int r = 0; r < 4; ++r) {
            const int row = b * 4096 + qbase + wave * 16 + quad * 4 + r;
            const int col = hoff + td * 16 + l15;
            Cmb[(size_t)row * 1280 + col] = f2bf(oC[td][r] * rc[r] + oI[td][r] * ri[r]);
        }
    }
}

// ---------- host launch ----------
extern "C" void kernel_launch(void* const* d_in, const int* in_sizes, int n_in,
                              void* d_out, int out_size, void* d_ws, size_t ws_size,
                              hipStream_t stream) {
    const float* hs  = (const float*)d_in[0];   // [4,4096,1280]
    const float* enc = (const float*)d_in[1];   // [4,77,2048]
    const float* idm = (const float*)d_in[2];   // [4,32,2048]
    const float* Wq  = (const float*)d_in[3];
    const float* Wk  = (const float*)d_in[4];
    const float* Wv  = (const float*)d_in[5];
    const float* Wik = (const float*)d_in[6];
    const float* Wiv = (const float*)d_in[7];
    const float* Wo  = (const float*)d_in[8];
    const float* bo  = (const float*)d_in[9];
    float* out = (float*)d_out;

    char* ws = (char*)d_ws;
    size_t off = 0;
    auto carve = [&](size_t bytes) {
        char* p = ws + off;
        off += (bytes + 255) & ~(size_t)255;
        return p;
    };

    unsigned short* Xh   = (unsigned short*)carve(16384ULL * 1280 * 2); // hs bf16, later 'combined'
    unsigned short* Wq_b = (unsigned short*)carve(1280ULL * 1280 * 2);
    unsigned short* Wk_b = (unsigned short*)carve(1280ULL * 2048 * 2);
    unsigned short* Wv_b = (unsigned short*)carve(1280ULL * 2048 * 2);
    unsigned short* Wik_b= (unsigned short*)carve(1280ULL * 2048 * 2);
    unsigned short* Wiv_b= (unsigned short*)carve(1280ULL * 2048 * 2);
    unsigned short* Wo_b = (unsigned short*)carve(1280ULL * 1280 * 2);
    unsigned short* Encb = (unsigned short*)carve(384ULL * 2048 * 2);  // per-batch padded 96 rows
    unsigned short* Idb  = (unsigned short*)carve(128ULL * 2048 * 2);
    unsigned short* Qb   = (unsigned short*)carve(16384ULL * 1280 * 2);
    unsigned short* Kb   = (unsigned short*)carve(384ULL * 1280 * 2);
    unsigned short* Vb   = (unsigned short*)carve(384ULL * 1280 * 2);
    unsigned short* IKb  = (unsigned short*)carve(128ULL * 1280 * 2);
    unsigned short* IVb  = (unsigned short*)carve(128ULL * 1280 * 2);
    (void)ws_size; (void)in_sizes; (void)n_in; (void)out_size;

    cast_bf16_kernel<<<(4 * 4096 * 1280 / 4 + 255) / 256, 256, 0, stream>>>(
        hs, Xh, 4 * 4096 * 1280);
    cast_enc_pad_kernel<<<(4 * 77 * 2048 / 4 + 255) / 256, 256, 0, stream>>>(enc, Encb);

    CastBatch cb;
    cb.src[0] = Wq;  cb.dst[0] = Wq_b;  cb.n[0] = 1280 * 1280;
    cb.src[1] = Wk;  cb.dst[1] = Wk_b;  cb.n[1] = 1280 * 2048;
    cb.src[2] = Wv;  cb.dst[2] = Wv_b;  cb.n[2] = 1280 * 2048;
    cb.src[3] = Wik; cb.dst[3] = Wik_b; cb.n[3] = 1280 * 2048;
    cb.src[4] = Wiv; cb.dst[4] = Wiv_b; cb.n[4] = 1280 * 2048;
    cb.src[5] = Wo;  cb.dst[5] = Wo_b;  cb.n[5] = 1280 * 1280;
    cb.src[6] = idm; cb.dst[6] = Idb;   cb.n[6] = 4 * 32 * 2048;
    cb.src[7] = nullptr; cb.dst[7] = nullptr; cb.n[7] = 0;
    cast_batch_kernel<<<dim3((1280 * 2048 / 4 + 255) / 256, 7), 256, 0, stream>>>(cb);

    // Q = hs @ Wq^T -> bf16   (256x320 tiles: 64x4 = 256 blocks, 1/CU, no tail)
    gemm320_kernel<1><<<dim3(64 * 4), 512, 0, stream>>>(
        Xh, Wq_b, nullptr, Qb, nullptr, nullptr, 1280, 1280, 4);

    // K/V/iK/iV projections -> bf16 (z=0..3), 64x128 tiles
    gemm_kv4_kernel<<<dim3(6, 10, 4), 256, 0, stream>>>(
        Encb, Idb, Wk_b, Wv_b, Wik_b, Wiv_b, Kb, Vb, IKb, IVb, 1280, 2048);

    // fused MFMA attention -> combined (reuses Xh)
    attn_mfma_kernel<<<dim3(64, 20, 4), 256, 0, stream>>>(Qb, Kb, Vb, IKb, IVb, Xh);

    // out = combined @ Wo^T + bo + residual
    gemm320_kernel<2><<<dim3(64 * 4), 512, 0, stream>>>(
        Xh, Wo_b, out, nullptr, bo, hs, 1280, 1280, 4);
}

// Round 7
// 416.835 us; speedup vs baseline: 1.1882x; 1.0164x over previous
//
#include <hip/hip_runtime.h>

// ---------- types ----------
typedef short short8 __attribute__((ext_vector_type(8)));
typedef unsigned short ushort8 __attribute__((ext_vector_type(8)));
typedef float float4v __attribute__((ext_vector_type(4)));

// ---------- bf16 helpers (bit-level) ----------
__device__ __forceinline__ unsigned short f2bf(float f) {
    union { float f; unsigned u; } v; v.f = f;
    unsigned r = v.u + 0x7fffu + ((v.u >> 16) & 1u);   // RNE
    return (unsigned short)(r >> 16);
}

// ---------- async global->LDS, 16B per lane ----------
__device__ __forceinline__ void async_copy16(const void* g, void* l) {
    __builtin_amdgcn_global_load_lds(
        (__attribute__((address_space(1))) void*)g,
        (__attribute__((address_space(3))) void*)l,
        16, 0, 0);
}

// ---------- merged fp32 -> bf16 cast (ALL tensors, one launch) ----------
// float4-granular regions, cumulative offsets hardcoded; grid = 34792 blocks
// x 256 = 8,906,752 float4 exactly (no bounds check). Regions are huge ->
// branch is wave-uniform except at boundaries. enc gets the 77->96 row pad.
// r6 BUG FIXED: enc per_b is 39424 float4 (77*2048/4), and the grid must
// cover 8,749,056 + 4*39,424 = 8,906,752 float4 (was 34,330 blocks -> 3/4 of
// enc never cast).
__global__ __launch_bounds__(256) void cast_all_kernel(
        const float* __restrict__ hs,  const float* __restrict__ enc,
        const float* __restrict__ idm, const float* __restrict__ Wq,
        const float* __restrict__ Wk,  const float* __restrict__ Wv,
        const float* __restrict__ Wik, const float* __restrict__ Wiv,
        const float* __restrict__ Wo,
        unsigned short* __restrict__ Xh,    unsigned short* __restrict__ Encb,
        unsigned short* __restrict__ Idb,   unsigned short* __restrict__ Wq_b,
        unsigned short* __restrict__ Wk_b,  unsigned short* __restrict__ Wv_b,
        unsigned short* __restrict__ Wik_b, unsigned short* __restrict__ Wiv_b,
        unsigned short* __restrict__ Wo_b) {
    const int g = blockIdx.x * 256 + threadIdx.x;   // float4 index
    const float* src; unsigned short* dst; int l4;
    if (g < 5242880)      { src = hs;  dst = Xh;    l4 = g; }            // 4*4096*1280/4
    else if (g < 5652480) { src = Wq;  dst = Wq_b;  l4 = g - 5242880; }  // 1280*1280/4
    else if (g < 6307840) { src = Wk;  dst = Wk_b;  l4 = g - 5652480; }  // 1280*2048/4
    else if (g < 6963200) { src = Wv;  dst = Wv_b;  l4 = g - 6307840; }
    else if (g < 7618560) { src = Wik; dst = Wik_b; l4 = g - 6963200; }
    else if (g < 8273920) { src = Wiv; dst = Wiv_b; l4 = g - 7618560; }
    else if (g < 8683520) { src = Wo;  dst = Wo_b;  l4 = g - 8273920; }
    else if (g < 8749056) { src = idm; dst = Idb;   l4 = g - 8683520; }  // 4*32*2048/4
    else {                                           // enc [4,77,2048] -> [4,96,2048]
        const int e = g - 8749056;                   // 0..157695
        const int b = e / 39424;                     // 77*2048/4 float4 per batch
        const int rem = e - b * 39424;
        float4 f = *(const float4*)(enc + (size_t)e * 4);
        ushort4 u;
        u.x = f2bf(f.x); u.y = f2bf(f.y); u.z = f2bf(f.z); u.w = f2bf(f.w);
        *(ushort4*)(Encb + ((size_t)b * 49152 + rem) * 4) = u;   // 96*2048/4 per batch
        return;
    }
    float4 f = *(const float4*)(src + (size_t)l4 * 4);
    ushort4 u;
    u.x = f2bf(f.x); u.y = f2bf(f.y); u.z = f2bf(f.z); u.w = f2bf(f.w);
    *(ushort4*)(dst + (size_t)l4 * 4) = u;
}

// ---------- 64x128-tile bf16 GEMM for the K/V projections ----------
// (unchanged from round 4)
__global__ __launch_bounds__(256) void gemm_kv4_kernel(
        const unsigned short* __restrict__ Aenc,   // [384,2048] per-batch padded
        const unsigned short* __restrict__ Aid,    // [128,2048]
        const unsigned short* __restrict__ Wk,
        const unsigned short* __restrict__ Wv,
        const unsigned short* __restrict__ Wik,
        const unsigned short* __restrict__ Wiv,
        unsigned short* __restrict__ Kb, unsigned short* __restrict__ Vb,
        unsigned short* __restrict__ IKb, unsigned short* __restrict__ IVb,
        int N, int K) {
    const int z = blockIdx.z;
    const int bm = blockIdx.x * 64;
    const int Mrows = (z < 2) ? 384 : 128;
    if (bm >= Mrows) return;
    const unsigned short* A = (z < 2) ? Aenc : Aid;
    const unsigned short* B = (z == 0) ? Wk : (z == 1) ? Wv : (z == 2) ? Wik : Wiv;
    unsigned short* C = (z == 0) ? Kb : (z == 1) ? Vb : (z == 2) ? IKb : IVb;
    const int bn = blockIdx.y * 128;

    __shared__ unsigned short As[64 * 64];    // 8 KB
    __shared__ unsigned short Bs[128 * 64];   // 16 KB

    const int tid  = threadIdx.x;
    const int lane = tid & 63;
    const int wave = tid >> 6;
    const int wm   = (wave >> 1) * 32;
    const int wn   = (wave & 1) * 64;
    const int lr   = lane & 15;
    const int lq   = lane >> 4;

    float4v acc[2][4] = {};

    const unsigned short* aptr[2];
    const unsigned short* bptr[4];
    #pragma unroll
    for (int r = 0; r < 2; ++r) {
        const int linear = r * 256 + tid;
        const int row = linear >> 3;
        const int c = (linear & 7) ^ (row & 7);
        aptr[r] = A + (size_t)(bm + row) * K + c * 8;
    }
    #pragma unroll
    for (int r = 0; r < 4; ++r) {
        const int linear = r * 256 + tid;
        const int row = linear >> 3;
        const int c = (linear & 7) ^ (row & 7);
        bptr[r] = B + (size_t)(bn + row) * K + c * 8;
    }

    for (int ks = 0; ks < K; ks += 64) {
        #pragma unroll
        for (int r = 0; r < 2; ++r)
            async_copy16(aptr[r] + ks, (char*)As + (size_t)(r * 256 + tid) * 16);
        #pragma unroll
        for (int r = 0; r < 4; ++r)
            async_copy16(bptr[r] + ks, (char*)Bs + (size_t)(r * 256 + tid) * 16);
        __syncthreads();

        #pragma unroll
        for (int kw = 0; kw < 2; ++kw) {
            short8 af[2], bfr[4];
            #pragma unroll
            for (int i = 0; i < 2; ++i) {
                const int row = wm + i * 16 + lr;
                af[i] = *(const short8*)(As + row * 64 + (((kw << 2) | lq) ^ (row & 7)) * 8);
            }
            #pragma unroll
            for (int j = 0; j < 4; ++j) {
                const int row = wn + j * 16 + lr;
                bfr[j] = *(const short8*)(Bs + row * 64 + (((kw << 2) | lq) ^ (row & 7)) * 8);
            }
            #pragma unroll
            for (int i = 0; i < 2; ++i)
                #pragma unroll
                for (int j = 0; j < 4; ++j)
                    acc[i][j] = __builtin_amdgcn_mfma_f32_16x16x32_bf16(
                                    af[i], bfr[j], acc[i][j], 0, 0, 0);
        }
        __syncthreads();
    }

    #pragma unroll
    for (int i = 0; i < 2; ++i) {
        #pragma unroll
        for (int r = 0; r < 4; ++r) {
            const int row = bm + wm + i * 16 + lq * 4 + r;
            const size_t base = (size_t)row * N;
            #pragma unroll
            for (int j = 0; j < 4; ++j) {
                const int col = bn + wn + j * 16 + lr;
                C[base + col] = f2bf(acc[i][j][r]);
            }
        }
    }
}

// ---------- 256x320-tile BK=32 GEMM, depth-3 prefetch ring ----------
// (structure unchanged from round 6 — never measured due to the cast bug;
// ring discipline re-audited: validate-before-read at top barrier, overwrite
// target (t+3)&3 = (t-1)&3 retired two barriers earlier, tail 10/8->5/4->0)
template<int EPI>
__global__ __launch_bounds__(512, 2) void gemm320_kernel(
        const unsigned short* __restrict__ A,
        const unsigned short* __restrict__ B,
        float* __restrict__ Cf,
        unsigned short* __restrict__ Cb,
        const float* __restrict__ bias,
        const float* __restrict__ resid,
        int N, int K, int tn) {           // tn = tiles along N (=4)
    __shared__ unsigned short As[4][256 * 32];   // 4 x 16 KB
    __shared__ unsigned short Bs[4][320 * 32];   // 4 x 20 KB  (144 KB total)

    const int tid  = threadIdx.x;
    const int lane = tid & 63;
    const int wave = tid >> 6;
    const int wm   = (wave >> 1) * 64;    // 4 wave-rows
    const int wn   = (wave & 1) * 160;    // 2 wave-cols
    const int l15  = lane & 15;
    const int lq   = lane >> 4;

    // XCD-bijective block swizzle (gridDim.x % 8 == 0)
    int wg = blockIdx.x;
    const int q = gridDim.x >> 3;
    wg = (wg & 7) * q + (wg >> 3);
    const int mt = wg / tn;
    const int nt = wg - mt * tn;
    const int bm = mt * 256;
    const int bn = nt * 320;

    float4v acc[4][10] = {};

    // staging address precompute. slot d -> row = d>>2, phys chunk = d&3,
    // logical chunk = phys ^ ((row>>1)&3) (involution; exact 2-way banks).
    const unsigned short* aS[2];
    const unsigned short* bS[2];
    const unsigned short* bS2;
    int dA[2], dB[2], dB2;
    #pragma unroll
    for (int g = 0; g < 2; ++g) {
        const int d = g * 512 + tid;
        const int row = d >> 2;
        const int c = (d & 3) ^ ((row >> 1) & 3);
        aS[g] = A + (size_t)(bm + row) * K + c * 8;
        bS[g] = B + (size_t)(bn + row) * K + c * 8;
        dA[g] = d * 16;
        dB[g] = d * 16;
    }
    {   // B rows 256..319: one extra load for threads 0..255 (waves 0-3)
        const int t2 = tid & 255;
        const int d = 1024 + t2;
        const int row = d >> 2;              // 256..319
        const int c = (d & 3) ^ ((row >> 1) & 3);
        bS2 = B + (size_t)(bn + row) * K + c * 8;
        dB2 = d * 16;
    }

    auto stage = [&](int t) {
        const int b = t & 3;
        #pragma unroll
        for (int g = 0; g < 2; ++g)
            async_copy16(aS[g] + t * 32, (char*)&As[b][0] + dA[g]);
        #pragma unroll
        for (int g = 0; g < 2; ++g)
            async_copy16(bS[g] + t * 32, (char*)&Bs[b][0] + dB[g]);
        if (wave < 4)
            async_copy16(bS2 + t * 32, (char*)&Bs[b][0] + dB2);
    };

    const int NT = K >> 5;        // 40
    stage(0);
    stage(1);
    stage(2);

    for (int t = 0; t < NT; ++t) {
        const int cur = t & 3;
        // validate tile t; keep tiles t+1,t+2 in flight (counted, not drained)
        if (t < NT - 2) {
            if (wave < 4) { asm volatile("s_waitcnt vmcnt(10)" ::: "memory"); }
            else          { asm volatile("s_waitcnt vmcnt(8)"  ::: "memory"); }
        } else if (t == NT - 2) {
            if (wave < 4) { asm volatile("s_waitcnt vmcnt(5)"  ::: "memory"); }
            else          { asm volatile("s_waitcnt vmcnt(4)"  ::: "memory"); }
        } else {
            asm volatile("s_waitcnt vmcnt(0)" ::: "memory");
        }
        __builtin_amdgcn_s_barrier();
        __builtin_amdgcn_sched_barrier(0);

        short8 af[4], bf[10];
        #pragma unroll
        for (int i = 0; i < 4; ++i) {
            const int row = wm + i * 16 + l15;
            af[i] = *(const short8*)(&As[cur][row * 32 + ((lq ^ ((row >> 1) & 3)) << 3)]);
        }
        #pragma unroll
        for (int j = 0; j < 10; ++j) {
            const int row = wn + j * 16 + l15;
            bf[j] = *(const short8*)(&Bs[cur][row * 32 + ((lq ^ ((row >> 1) & 3)) << 3)]);
        }
        asm volatile("s_waitcnt lgkmcnt(0)" ::: "memory");
        __builtin_amdgcn_sched_barrier(0);
        if (t < NT - 3) {
            __builtin_amdgcn_s_barrier();   // all waves past their reads
            stage(t + 3);                   // ring slot (t+3)&3 = (t-1)&3
        }
        __builtin_amdgcn_s_setprio(1);
        #pragma unroll
        for (int i = 0; i < 4; ++i)
            #pragma unroll
            for (int j = 0; j < 10; ++j)
                acc[i][j] = __builtin_amdgcn_mfma_f32_16x16x32_bf16(
                                af[i], bf[j], acc[i][j], 0, 0, 0);
        __builtin_amdgcn_s_setprio(0);
    }

    // C/D layout: col=lane&15, row=(lane>>4)*4+reg   [m89-verified]
    #pragma unroll
    for (int i = 0; i < 4; ++i) {
        #pragma unroll
        for (int r = 0; r < 4; ++r) {
            const int row = bm + wm + i * 16 + lq * 4 + r;
            const size_t base = (size_t)row * N;
            #pragma unroll
            for (int j = 0; j < 10; ++j) {
                const int col = bn + wn + j * 16 + l15;
                const float v = acc[i][j][r];
                const size_t idx = base + col;
                if (EPI == 2)      Cf[idx] = v + bias[col] + resid[idx];
                else if (EPI == 1) Cb[idx] = f2bf(v);
                else               Cf[idx] = v;
            }
        }
    }
}

// ---------- MFMA fused dual attention ----------
#define VT_STRIDE 136
__global__ __launch_bounds__(256) void attn_mfma_kernel(
        const unsigned short* __restrict__ Q,     // [16384,1280] bf16
        const unsigned short* __restrict__ Kb,    // [384,1280]  bf16, rows b*96+t
        const unsigned short* __restrict__ Vb,    // [384,1280]  bf16
        const unsigned short* __restrict__ IKb,   // [128,1280]  bf16, rows b*32+t
        const unsigned short* __restrict__ IVb,   // [128,1280]  bf16
        unsigned short* __restrict__ Cmb) {       // [16384,1280] bf16
    const int b = blockIdx.z;
    const int h = blockIdx.y;
    const int hoff = h * 64;
    const int qbase = blockIdx.x * 64;
    const int tid = threadIdx.x;
    const int lane = tid & 63;
    const int wave = tid >> 6;
    const int l15 = lane & 15;
    const int quad = lane >> 4;

    __shared__ unsigned short Vt[64 * VT_STRIDE];  // [d][key] cross 0..95, id 96..127
    __shared__ unsigned short Pl[64 * VT_STRIDE];  // [qrow][key]

    for (int i = tid; i < 96 * 8; i += 256) {
        const int c = i / 96;
        const int key = i - c * 96;
        short8 v = *(const short8*)(Vb + (size_t)(b * 96 + key) * 1280 + hoff + c * 8);
        #pragma unroll
        for (int j = 0; j < 8; ++j)
            Vt[(c * 8 + j) * VT_STRIDE + key] = (unsigned short)v[j];
    }
    {
        const int c = tid >> 5;
        const int key = tid & 31;
        short8 v = *(const short8*)(IVb + (size_t)(b * 32 + key) * 1280 + hoff + c * 8);
        #pragma unroll
        for (int j = 0; j < 8; ++j)
            Vt[(c * 8 + j) * VT_STRIDE + 96 + key] = (unsigned short)v[j];
    }
    __syncthreads();

    const int qrow = b * 4096 + qbase + wave * 16 + l15;
    const unsigned short* qp = Q + (size_t)qrow * 1280 + hoff + quad * 8;
    const short8 aQ0 = *(const short8*)(qp);
    const short8 aQ1 = *(const short8*)(qp + 32);

    const float scale = 0.125f;
    float lC[4] = {0.f, 0.f, 0.f, 0.f};
    float lI[4] = {0.f, 0.f, 0.f, 0.f};

    #pragma unroll
    for (int t = 0; t < 5; ++t) {
        const unsigned short* kp = Kb + (size_t)(b * 96 + t * 16 + l15) * 1280 + hoff + quad * 8;
        const short8 bK0 = *(const short8*)(kp);
        const short8 bK1 = *(const short8*)(kp + 32);
        float4v s = {};
        s = __builtin_amdgcn_mfma_f32_16x16x32_bf16(aQ0, bK0, s, 0, 0, 0);
        s = __builtin_amdgcn_mfma_f32_16x16x32_bf16(aQ1, bK1, s, 0, 0, 0);
        #pragma unroll
        for (int r = 0; r < 4; ++r) {
            float p = __expf(s[r] * scale);
            if (t == 4 && l15 >= 13) p = 0.f;   // keys 77..79 masked
            lC[r] += p;
            Pl[(wave * 16 + quad * 4 + r) * VT_STRIDE + t * 16 + l15] = f2bf(p);
        }
    }
    #pragma unroll
    for (int r = 0; r < 4; ++r)
        Pl[(wave * 16 + quad * 4 + r) * VT_STRIDE + 80 + l15] = 0;

    #pragma unroll
    for (int t = 0; t < 2; ++t) {
        const unsigned short* kp = IKb + (size_t)(b * 32 + t * 16 + l15) * 1280 + hoff + quad * 8;
        const short8 bK0 = *(const short8*)(kp);
        const short8 bK1 = *(const short8*)(kp + 32);
        float4v s = {};
        s = __builtin_amdgcn_mfma_f32_16x16x32_bf16(aQ0, bK0, s, 0, 0, 0);
        s = __builtin_amdgcn_mfma_f32_16x16x32_bf16(aQ1, bK1, s, 0, 0, 0);
        #pragma unroll
        for (int r = 0; r < 4; ++r) {
            const float p = __expf(s[r] * scale);
            lI[r] += p;
            Pl[(wave * 16 + quad * 4 + r) * VT_STRIDE + 96 + t * 16 + l15] = f2bf(p);
        }
    }

    #pragma unroll
    for (int m = 1; m <= 8; m <<= 1) {
        #pragma unroll
        for (int r = 0; r < 4; ++r) {
            lC[r] += __shfl_xor(lC[r], m);
            lI[r] += __shfl_xor(lI[r], m);
        }
    }
    __syncthreads();

    float4v oC[4] = {};
    float4v oI[4] = {};
    #pragma unroll
    for (int kt = 0; kt < 3; ++kt) {
        const short8 aP = *(const short8*)(Pl + (wave * 16 + l15) * VT_STRIDE + kt * 32 + quad * 8);
        #pragma unroll
        for (int td = 0; td < 4; ++td) {
            const short8 bV = *(const short8*)(Vt + (td * 16 + l15) * VT_STRIDE + kt * 32 + quad * 8);
            oC[td] = __builtin_amdgcn_mfma_f32_16x16x32_bf16(aP, bV, oC[td], 0, 0, 0);
        }
    }
    {
        const short8 aP = *(const short8*)(Pl + (wave * 16 + l15) * VT_STRIDE + 96 + quad * 8);
        #pragma unroll
        for (int td = 0; td < 4; ++td) {
            const short8 bV = *(const short8*)(Vt + (td * 16 + l15) * VT_STRIDE + 96 + quad * 8);
            oI[td] = __builtin_amdgcn_mfma_f32_16x16x32_bf16(aP, bV, oI[td], 0, 0, 0);
        }
    }

    float rc[4], ri[4];
    #pragma unroll
    for (int r = 0; r < 4; ++r) { rc[r] = 1.f / lC[r]; ri[r] = 1.f / lI[r]; }

    #pragma unroll
    for (int td = 0; td < 4; ++td) {
        #pragma unroll
        for (int r = 0; r < 4; ++r) {
            const int row = b * 4096 + qbase + wave * 16 + quad * 4 + r;
            const int col = hoff + td * 16 + l15;
            Cmb[(size_t)row * 1280 + col] = f2bf(oC[td][r] * rc[r] + oI[td][r] * ri[r]);
        }
    }
}

// ---------- host launch ----------
extern "C" void kernel_launch(void* const* d_in, const int* in_sizes, int n_in,
                              void* d_out, int out_size, void* d_ws, size_t ws_size,
                              hipStream_t stream) {
    const float* hs  = (const float*)d_in[0];   // [4,4096,1280]
    const float* enc = (const float*)d_in[1];   // [4,77,2048]
    const float* idm = (const float*)d_in[2];   // [4,32,2048]
    const float* Wq  = (const float*)d_in[3];
    const float* Wk  = (const float*)d_in[4];
    const float* Wv  = (const float*)d_in[5];
    const float* Wik = (const float*)d_in[6];
    const float* Wiv = (const float*)d_in[7];
    const float* Wo  = (const float*)d_in[8];
    const float* bo  = (const float*)d_in[9];
    float* out = (float*)d_out;

    char* ws = (char*)d_ws;
    size_t off = 0;
    auto carve = [&](size_t bytes) {
        char* p = ws + off;
        off += (bytes + 255) & ~(size_t)255;
        return p;
    };

    unsigned short* Xh   = (unsigned short*)carve(16384ULL * 1280 * 2); // hs bf16, later 'combined'
    unsigned short* Wq_b = (unsigned short*)carve(1280ULL * 1280 * 2);
    unsigned short* Wk_b = (unsigned short*)carve(1280ULL * 2048 * 2);
    unsigned short* Wv_b = (unsigned short*)carve(1280ULL * 2048 * 2);
    unsigned short* Wik_b= (unsigned short*)carve(1280ULL * 2048 * 2);
    unsigned short* Wiv_b= (unsigned short*)carve(1280ULL * 2048 * 2);
    unsigned short* Wo_b = (unsigned short*)carve(1280ULL * 1280 * 2);
    unsigned short* Encb = (unsigned short*)carve(384ULL * 2048 * 2);  // per-batch padded 96 rows
    unsigned short* Idb  = (unsigned short*)carve(128ULL * 2048 * 2);
    unsigned short* Qb   = (unsigned short*)carve(16384ULL * 1280 * 2);
    unsigned short* Kb   = (unsigned short*)carve(384ULL * 1280 * 2);
    unsigned short* Vb   = (unsigned short*)carve(384ULL * 1280 * 2);
    unsigned short* IKb  = (unsigned short*)carve(128ULL * 1280 * 2);
    unsigned short* IVb  = (unsigned short*)carve(128ULL * 1280 * 2);
    (void)ws_size; (void)in_sizes; (void)n_in; (void)out_size;

    // all casts in one launch (34792 x 256 = 8,906,752 float4 exactly)
    cast_all_kernel<<<34792, 256, 0, stream>>>(
        hs, enc, idm, Wq, Wk, Wv, Wik, Wiv, Wo,
        Xh, Encb, Idb, Wq_b, Wk_b, Wv_b, Wik_b, Wiv_b, Wo_b);

    // Q = hs @ Wq^T -> bf16   (256x320 tiles, depth-3 ring: 256 blocks, 1/CU)
    gemm320_kernel<1><<<dim3(64 * 4), 512, 0, stream>>>(
        Xh, Wq_b, nullptr, Qb, nullptr, nullptr, 1280, 1280, 4);

    // K/V/iK/iV projections -> bf16 (z=0..3), 64x128 tiles
    gemm_kv4_kernel<<<dim3(6, 10, 4), 256, 0, stream>>>(
        Encb, Idb, Wk_b, Wv_b, Wik_b, Wiv_b, Kb, Vb, IKb, IVb, 1280, 2048);

    // fused MFMA attention -> combined (reuses Xh)
    attn_mfma_kernel<<<dim3(64, 20, 4), 256, 0, stream>>>(Qb, Kb, Vb, IKb, IVb, Xh);

    // out = combined @ Wo^T + bo + residual
    gemm320_kernel<2><<<dim3(64 * 4), 512, 0, stream>>>(
        Xh, Wo_b, out, nullptr, bo, hs, 1280, 1280, 4);
}